// Round 8
// baseline (104.242 us; speedup 1.0000x reference)
//
#include <hip/hip_runtime.h>

// RBF Gram via bf16-split MFMA, two-phase, zero-LDS phase 2:
//   P1: x (fp32 [N][64]) -> Xh,Xl (bf16 row-major [N][64]) + sq[N] in d_ws
//   P2: 128x128 tile/block, MFMA fragments loaded DIRECTLY from L1/L2-resident
//       Xh/Xl (each wave-load = 16 rows x 64B = 16 fully-used granules, no LDS,
//       no barriers). dot = hh + hl + lh (lo*lo dropped, ~1e-4 << 2e-2 thresh).
//       Swapped-operand MFMA gives D^T so each lane owns 4 consecutive output
//       cols -> dwordx4 stores. out[i,j] = exp(-0.5*(sq_i+sq_j-2dot)).

#define GAMMA 0.5f

typedef __attribute__((ext_vector_type(8))) short short8;
typedef __attribute__((ext_vector_type(4))) float f32x4;

__device__ __forceinline__ unsigned short bf16_rne(float f) {
    unsigned u = __builtin_bit_cast(unsigned, f);
    u += 0x7fffu + ((u >> 16) & 1u);
    return (unsigned short)(u >> 16);
}

// ---------------- Phase 1: split + norms ----------------
__global__ __launch_bounds__(256) void split_kernel(const float* __restrict__ x,
                                                    unsigned short* __restrict__ Xh,
                                                    unsigned short* __restrict__ Xl,
                                                    float* __restrict__ sq) {
    int tid = blockIdx.x * 256 + threadIdx.x;   // one float4 (4 elems of one row)
    int row = tid >> 4, c4 = tid & 15;
    float4 v = ((const float4*)x)[tid];
    float e[4] = {v.x, v.y, v.z, v.w};
    unsigned short h[4], l[4];
    float s = 0.f;
    #pragma unroll
    for (int i = 0; i < 4; ++i) {
        h[i] = bf16_rne(e[i]);
        float hf = __builtin_bit_cast(float, (unsigned)h[i] << 16);
        l[i] = bf16_rne(e[i] - hf);
        s = fmaf(e[i], e[i], s);
    }
    uint2 hw = {(unsigned)h[0] | ((unsigned)h[1] << 16), (unsigned)h[2] | ((unsigned)h[3] << 16)};
    uint2 lw = {(unsigned)l[0] | ((unsigned)l[1] << 16), (unsigned)l[2] | ((unsigned)l[3] << 16)};
    *(uint2*)&Xh[(size_t)row * 64 + c4 * 4] = hw;
    *(uint2*)&Xl[(size_t)row * 64 + c4 * 4] = lw;
    s += __shfl_xor(s, 1); s += __shfl_xor(s, 2);
    s += __shfl_xor(s, 4); s += __shfl_xor(s, 8);
    if (c4 == 0) sq[row] = s;
}

// ---------------- Phase 2: LDS-free MFMA + exp epilogue ----------------
__global__ __launch_bounds__(256) void rbf_mfma3(const unsigned short* __restrict__ Xh,
                                                 const unsigned short* __restrict__ Xl,
                                                 const float* __restrict__ sq,
                                                 float* __restrict__ out, int N) {
    const int tid = threadIdx.x;
    const int i0 = blockIdx.y * 128, j0 = blockIdx.x * 128;
    const int w = tid >> 6, lane = tid & 63;
    const int fr = lane & 15, kg = lane >> 4;
    const int wr = (w >> 1) * 64, wc = (w & 1) * 64;   // wave quadrant of 128x128

    f32x4 acc[4][4];
    #pragma unroll
    for (int p = 0; p < 4; ++p)
        #pragma unroll
        for (int q = 0; q < 4; ++q) acc[p][q] = (f32x4)(0.f);

    #pragma unroll
    for (int ks = 0; ks < 2; ++ks) {
        const int k = ks * 32 + kg * 8;   // this lane's 8-elem k-slice
        short8 ah[4], al[4], bh[4], bl[4];
        #pragma unroll
        for (int p = 0; p < 4; ++p) {
            size_t off = (size_t)(i0 + wr + p * 16 + fr) * 64 + k;
            ah[p] = *(const short8*)(Xh + off);
            al[p] = *(const short8*)(Xl + off);
        }
        #pragma unroll
        for (int q = 0; q < 4; ++q) {
            size_t off = (size_t)(j0 + wc + q * 16 + fr) * 64 + k;
            bh[q] = *(const short8*)(Xh + off);
            bl[q] = *(const short8*)(Xl + off);
        }
        #pragma unroll
        for (int p = 0; p < 4; ++p)
            #pragma unroll
            for (int q = 0; q < 4; ++q)
                acc[p][q] = __builtin_amdgcn_mfma_f32_16x16x32_bf16(bh[q], ah[p], acc[p][q], 0, 0, 0);
        #pragma unroll
        for (int p = 0; p < 4; ++p)
            #pragma unroll
            for (int q = 0; q < 4; ++q)
                acc[p][q] = __builtin_amdgcn_mfma_f32_16x16x32_bf16(bl[q], ah[p], acc[p][q], 0, 0, 0);
        #pragma unroll
        for (int p = 0; p < 4; ++p)
            #pragma unroll
            for (int q = 0; q < 4; ++q)
                acc[p][q] = __builtin_amdgcn_mfma_f32_16x16x32_bf16(bh[q], al[p], acc[p][q], 0, 0, 0);
    }

    // ---- epilogue: D^T layout => lane holds row (i0+wr+p*16+fr), cols (wc+q*16+kg*4 .. +3)
    #pragma unroll
    for (int p = 0; p < 4; ++p) {
        int ri = wr + p * 16 + fr;
        float sa = sq[i0 + ri];
        float* rowp = out + (size_t)(i0 + ri) * N + j0;
        #pragma unroll
        for (int q = 0; q < 4; ++q) {
            int c = wc + q * 16 + kg * 4;
            float4 sb = *(const float4*)&sq[j0 + c];
            f32x4 a = acc[p][q];
            float4 r;
            r.x = __expf(-GAMMA * fmaxf(fmaf(-2.f, a[0], sa + sb.x), 0.f));
            r.y = __expf(-GAMMA * fmaxf(fmaf(-2.f, a[1], sa + sb.y), 0.f));
            r.z = __expf(-GAMMA * fmaxf(fmaf(-2.f, a[2], sa + sb.z), 0.f));
            r.w = __expf(-GAMMA * fmaxf(fmaf(-2.f, a[3], sa + sb.w), 0.f));
            *(float4*)(rowp + c) = r;
        }
    }
}

extern "C" void kernel_launch(void* const* d_in, const int* in_sizes, int n_in,
                              void* d_out, int out_size, void* d_ws, size_t ws_size,
                              hipStream_t stream) {
    (void)n_in; (void)ws_size; (void)out_size;
    const float* x = (const float*)d_in[0];
    float* out = (float*)d_out;
    const int K = 64;
    const int N = in_sizes[0] / K;   // 8192

    unsigned short* Xh = (unsigned short*)d_ws;              // N*64 bf16 = 1 MB
    unsigned short* Xl = Xh + (size_t)N * K;                 // 1 MB
    float* sq = (float*)(Xl + (size_t)N * K);                // 32 KB

    split_kernel<<<dim3(N * K / 4 / 256), dim3(256), 0, stream>>>(x, Xh, Xl, sq);
    rbf_mfma3<<<dim3(N / 128, N / 128), dim3(256), 0, stream>>>(Xh, Xl, sq, out, N);
}

// Round 9
// 99.409 us; speedup vs baseline: 1.0486x; 1.0486x over previous
//
#include <hip/hip_runtime.h>

// RBF Gram via bf16-split MFMA, two-phase, persistent-block phase 2:
//   P1: x (fp32 [N][64]) -> Xh,Xl (bf16, XOR-swizzled per 128-row chunk) + sq[N] in d_ws
//   P2: 512 persistent blocks (2/CU), each owns one 128-row A panel (staged to LDS once)
//       and walks 8 column tiles; B tile prefetched to regs (T14) while computing the
//       previous tile. dot = hh + hl + lh on matrix cores (lo*lo dropped, ~1e-13 here).
//       Swapped-operand MFMA -> D^T -> dwordx4 stores. out = exp(-0.5*(sq_i+sq_j-2dot)).

#define GAMMA 0.5f

typedef __attribute__((ext_vector_type(8))) short short8;
typedef __attribute__((ext_vector_type(4))) float f32x4;

__device__ __forceinline__ unsigned short bf16_rne(float f) {
    unsigned u = __builtin_bit_cast(unsigned, f);
    u += 0x7fffu + ((u >> 16) & 1u);
    return (unsigned short)(u >> 16);
}

// ---------------- Phase 1: split + swizzle + norms ----------------
__global__ __launch_bounds__(256) void split_kernel(const float* __restrict__ x,
                                                    unsigned short* __restrict__ Xh,
                                                    unsigned short* __restrict__ Xl,
                                                    float* __restrict__ sq) {
    int tid = blockIdx.x * 256 + threadIdx.x;   // one float4 (4 elems of one row)
    int row = tid >> 4, c4 = tid & 15;
    float4 v = ((const float4*)x)[tid];
    float e[4] = {v.x, v.y, v.z, v.w};
    unsigned short h[4], l[4];
    float s = 0.f;
    #pragma unroll
    for (int i = 0; i < 4; ++i) {
        h[i] = bf16_rne(e[i]);
        float hf = __builtin_bit_cast(float, (unsigned)h[i] << 16);
        l[i] = bf16_rne(e[i] - hf);
        s = fmaf(e[i], e[i], s);
    }
    // byte offset within the 16KB 128-row chunk, XOR-swizzled (bits 4..6 by row&7)
    int rr = row & 127;
    size_t base = (size_t)(row >> 7) * 16384;
    int b = (rr * 128 + c4 * 8) ^ ((rr & 7) << 4);
    uint2 hw = {(unsigned)h[0] | ((unsigned)h[1] << 16), (unsigned)h[2] | ((unsigned)h[3] << 16)};
    uint2 lw = {(unsigned)l[0] | ((unsigned)l[1] << 16), (unsigned)l[2] | ((unsigned)l[3] << 16)};
    *(uint2*)((char*)Xh + base + b) = hw;
    *(uint2*)((char*)Xl + base + b) = lw;
    s += __shfl_xor(s, 1); s += __shfl_xor(s, 2);
    s += __shfl_xor(s, 4); s += __shfl_xor(s, 8);
    if (c4 == 0) sq[row] = s;
}

// ---------------- Phase 2: persistent tiled MFMA + exp epilogue ----------------
__global__ __launch_bounds__(256, 2) void rbf_mfma4(const unsigned short* __restrict__ Xh,
                                                    const unsigned short* __restrict__ Xl,
                                                    const float* __restrict__ sq,
                                                    float* __restrict__ out, int N) {
    __shared__ unsigned short Ah[8192], Al[8192], Bh[8192], Bl[8192];  // 64 KB

    const int tid = threadIdx.x;
    const int bi  = blockIdx.x >> 3;          // 64 block-rows
    const int bj0 = (blockIdx.x & 7) * 8;     // 8 column-tiles per block
    const int i0  = bi * 128;

    const int w = tid >> 6, lane = tid & 63;
    const int fr = lane & 15, kg = lane >> 4;
    const int wr = (w >> 1) * 64, wc = (w & 1) * 64;   // wave quadrant of 128x128

    // ---- stage A panel ONCE (linear 32KB copy; swizzle pre-baked in global) ----
    {
        const uint4* gh = (const uint4*)(Xh + (size_t)i0 * 64);
        const uint4* gl = (const uint4*)(Xl + (size_t)i0 * 64);
        #pragma unroll
        for (int t = 0; t < 4; ++t) {
            ((uint4*)Ah)[t * 256 + tid] = gh[t * 256 + tid];
            ((uint4*)Al)[t * 256 + tid] = gl[t * 256 + tid];
        }
    }
    // ---- prefetch B tile 0 into regs (T14) ----
    uint4 ph[4], pl[4];
    {
        const uint4* gh = (const uint4*)(Xh + (size_t)bj0 * 128 * 64);
        const uint4* gl = (const uint4*)(Xl + (size_t)bj0 * 128 * 64);
        #pragma unroll
        for (int t = 0; t < 4; ++t) { ph[t] = gh[t * 256 + tid]; pl[t] = gl[t * 256 + tid]; }
    }

    for (int tj = 0; tj < 8; ++tj) {
        const int j0 = (bj0 + tj) * 128;
        __syncthreads();                       // prev tile's ds_reads (and A-stage) done
        #pragma unroll
        for (int t = 0; t < 4; ++t) {          // B regs -> LDS
            ((uint4*)Bh)[t * 256 + tid] = ph[t];
            ((uint4*)Bl)[t * 256 + tid] = pl[t];
        }
        __syncthreads();
        if (tj < 7) {                          // prefetch next B; hides under compute below
            const uint4* gh = (const uint4*)(Xh + (size_t)(j0 + 128) * 64);
            const uint4* gl = (const uint4*)(Xl + (size_t)(j0 + 128) * 64);
            #pragma unroll
            for (int t = 0; t < 4; ++t) { ph[t] = gh[t * 256 + tid]; pl[t] = gl[t * 256 + tid]; }
        }

        // ---- K-loop: 2 ksteps x 3 passes (hh, hl, lh), swapped operands -> D^T ----
        f32x4 acc[4][4];
        #pragma unroll
        for (int p = 0; p < 4; ++p)
            #pragma unroll
            for (int q = 0; q < 4; ++q) acc[p][q] = (f32x4)(0.f);

        #pragma unroll
        for (int ks = 0; ks < 2; ++ks) {
            const int kb = ks * 64 + kg * 16;  // byte offset of this lane's 16B k-slice
            short8 ah[4], al[4], bh[4], bl[4];
            #pragma unroll
            for (int p = 0; p < 4; ++p) {
                int R = wr + p * 16 + fr;
                int off = (R * 128 + kb) ^ ((R & 7) << 4);
                ah[p] = *(const short8*)((const char*)Ah + off);
                al[p] = *(const short8*)((const char*)Al + off);
            }
            #pragma unroll
            for (int q = 0; q < 4; ++q) {
                int R = wc + q * 16 + fr;
                int off = (R * 128 + kb) ^ ((R & 7) << 4);
                bh[q] = *(const short8*)((const char*)Bh + off);
                bl[q] = *(const short8*)((const char*)Bl + off);
            }
            #pragma unroll
            for (int p = 0; p < 4; ++p)
                #pragma unroll
                for (int q = 0; q < 4; ++q)
                    acc[p][q] = __builtin_amdgcn_mfma_f32_16x16x32_bf16(bh[q], ah[p], acc[p][q], 0, 0, 0);
            #pragma unroll
            for (int p = 0; p < 4; ++p)
                #pragma unroll
                for (int q = 0; q < 4; ++q)
                    acc[p][q] = __builtin_amdgcn_mfma_f32_16x16x32_bf16(bl[q], ah[p], acc[p][q], 0, 0, 0);
            #pragma unroll
            for (int p = 0; p < 4; ++p)
                #pragma unroll
                for (int q = 0; q < 4; ++q)
                    acc[p][q] = __builtin_amdgcn_mfma_f32_16x16x32_bf16(bh[q], al[p], acc[p][q], 0, 0, 0);
        }

        // ---- epilogue: D^T => lane holds row (i0+wr+p*16+fr), cols (wc+q*16+kg*4..+3)
        #pragma unroll
        for (int p = 0; p < 4; ++p) {
            int ri = wr + p * 16 + fr;
            float sa = sq[i0 + ri];
            float* rowp = out + (size_t)(i0 + ri) * N + j0;
            #pragma unroll
            for (int q = 0; q < 4; ++q) {
                int c = wc + q * 16 + kg * 4;
                float4 sb = *(const float4*)&sq[j0 + c];
                f32x4 a = acc[p][q];
                float4 r;
                r.x = __expf(-GAMMA * fmaxf(fmaf(-2.f, a[0], sa + sb.x), 0.f));
                r.y = __expf(-GAMMA * fmaxf(fmaf(-2.f, a[1], sa + sb.y), 0.f));
                r.z = __expf(-GAMMA * fmaxf(fmaf(-2.f, a[2], sa + sb.z), 0.f));
                r.w = __expf(-GAMMA * fmaxf(fmaf(-2.f, a[3], sa + sb.w), 0.f));
                *(float4*)(rowp + c) = r;
            }
        }
    }
}

extern "C" void kernel_launch(void* const* d_in, const int* in_sizes, int n_in,
                              void* d_out, int out_size, void* d_ws, size_t ws_size,
                              hipStream_t stream) {
    (void)n_in; (void)ws_size; (void)out_size;
    const float* x = (const float*)d_in[0];
    float* out = (float*)d_out;
    const int K = 64;
    const int N = in_sizes[0] / K;   // 8192

    unsigned short* Xh = (unsigned short*)d_ws;              // N*64 bf16 = 1 MB
    unsigned short* Xl = Xh + (size_t)N * K;                 // 1 MB
    float* sq = (float*)(Xl + (size_t)N * K);                // 32 KB

    split_kernel<<<dim3(N * K / 4 / 256), dim3(256), 0, stream>>>(x, Xh, Xl, sq);
    // 64 block-rows x 8 column-groups = 512 persistent blocks (2/CU)
    rbf_mfma4<<<dim3((N / 128) * 8), dim3(256), 0, stream>>>(Xh, Xl, sq, out, N);
}

// Round 10
// 71.563 us; speedup vs baseline: 1.4567x; 1.3891x over previous
//
#include <hip/hip_runtime.h>

// RBF Gram via bf16-split MFMA, two-phase:
//   P1: x (fp32 [N][64]) -> Xh,Xl (bf16, XOR-swizzled per 128-row chunk) + sq[N] in d_ws
//   P2: 64x128 tiles (A=64 rows, B=128 cols), LDS 48 KB -> 3 blocks/CU, 8192 blocks.
//       dot = hh + hl + lh on matrix cores (lo*lo dropped; exact to ~1e-13 here).
//       Swapped-operand MFMA (D^T) so each lane owns 4 consecutive out cols -> dwordx4.
//       out = exp(-0.5*(sq_i+sq_j-2dot)).

#define GAMMA 0.5f

typedef __attribute__((ext_vector_type(8))) short short8;
typedef __attribute__((ext_vector_type(4))) float f32x4;

__device__ __forceinline__ unsigned short bf16_rne(float f) {
    unsigned u = __builtin_bit_cast(unsigned, f);
    u += 0x7fffu + ((u >> 16) & 1u);
    return (unsigned short)(u >> 16);
}

// ---------------- Phase 1: split + swizzle + norms ----------------
__global__ __launch_bounds__(256) void split_kernel(const float* __restrict__ x,
                                                    unsigned short* __restrict__ Xh,
                                                    unsigned short* __restrict__ Xl,
                                                    float* __restrict__ sq) {
    int tid = blockIdx.x * 256 + threadIdx.x;   // one float4 (4 elems of one row)
    int row = tid >> 4, c4 = tid & 15;
    float4 v = ((const float4*)x)[tid];
    float e[4] = {v.x, v.y, v.z, v.w};
    unsigned short h[4], l[4];
    float s = 0.f;
    #pragma unroll
    for (int i = 0; i < 4; ++i) {
        h[i] = bf16_rne(e[i]);
        float hf = __builtin_bit_cast(float, (unsigned)h[i] << 16);
        l[i] = bf16_rne(e[i] - hf);
        s = fmaf(e[i], e[i], s);
    }
    // byte offset within the 16KB 128-row chunk; XOR is row-local (bits 4..6 by row&7)
    int rr = row & 127;
    size_t base = (size_t)(row >> 7) * 16384;
    int b = (rr * 128 + c4 * 8) ^ ((rr & 7) << 4);
    uint2 hw = {(unsigned)h[0] | ((unsigned)h[1] << 16), (unsigned)h[2] | ((unsigned)h[3] << 16)};
    uint2 lw = {(unsigned)l[0] | ((unsigned)l[1] << 16), (unsigned)l[2] | ((unsigned)l[3] << 16)};
    *(uint2*)((char*)Xh + base + b) = hw;
    *(uint2*)((char*)Xl + base + b) = lw;
    s += __shfl_xor(s, 1); s += __shfl_xor(s, 2);
    s += __shfl_xor(s, 4); s += __shfl_xor(s, 8);
    if (c4 == 0) sq[row] = s;
}

// ---------------- Phase 2: 64x128-tile MFMA + exp epilogue ----------------
__global__ __launch_bounds__(256) void rbf_mfma5(const unsigned short* __restrict__ Xh,
                                                 const unsigned short* __restrict__ Xl,
                                                 const float* __restrict__ sq,
                                                 float* __restrict__ out, int N) {
    // A: 64 rows (8 KB x2), B: 128 rows (16 KB x2) -> 48 KB total
    __shared__ unsigned short Ah[4096], Al[4096], Bh[8192], Bl[8192];

    const int tid = threadIdx.x;
    const int i0 = blockIdx.y * 64, j0 = blockIdx.x * 128;
    const int w = tid >> 6, lane = tid & 63;
    const int fr = lane & 15, kg = lane >> 4;
    const int wr = (w >> 1) * 32, wc = (w & 1) * 64;   // wave sub-tile 32x64

    // ---- stage: linear copies (swizzle pre-baked in global; row-local XOR) ----
    {
        const uint4* gha = (const uint4*)(Xh + (size_t)i0 * 64);
        const uint4* gla = (const uint4*)(Xl + (size_t)i0 * 64);
        const uint4* ghb = (const uint4*)(Xh + (size_t)j0 * 64);
        const uint4* glb = (const uint4*)(Xl + (size_t)j0 * 64);
        #pragma unroll
        for (int t = 0; t < 2; ++t) {
            ((uint4*)Ah)[t * 256 + tid] = gha[t * 256 + tid];
            ((uint4*)Al)[t * 256 + tid] = gla[t * 256 + tid];
        }
        #pragma unroll
        for (int t = 0; t < 4; ++t) {
            ((uint4*)Bh)[t * 256 + tid] = ghb[t * 256 + tid];
            ((uint4*)Bl)[t * 256 + tid] = glb[t * 256 + tid];
        }
    }
    __syncthreads();

    // ---- K-loop: 2 ksteps x 3 passes (hh, hl, lh), swapped operands -> D^T ----
    f32x4 acc[2][4];
    #pragma unroll
    for (int p = 0; p < 2; ++p)
        #pragma unroll
        for (int q = 0; q < 4; ++q) acc[p][q] = (f32x4)(0.f);

    #pragma unroll
    for (int ks = 0; ks < 2; ++ks) {
        const int kb = ks * 64 + kg * 16;   // byte offset of this lane's 16B k-slice
        short8 ah[2], al[2], bh[4], bl[4];
        #pragma unroll
        for (int p = 0; p < 2; ++p) {
            int R = wr + p * 16 + fr;
            int off = (R * 128 + kb) ^ ((R & 7) << 4);
            ah[p] = *(const short8*)((const char*)Ah + off);
            al[p] = *(const short8*)((const char*)Al + off);
        }
        #pragma unroll
        for (int q = 0; q < 4; ++q) {
            int R = wc + q * 16 + fr;
            int off = (R * 128 + kb) ^ ((R & 7) << 4);
            bh[q] = *(const short8*)((const char*)Bh + off);
            bl[q] = *(const short8*)((const char*)Bl + off);
        }
        #pragma unroll
        for (int p = 0; p < 2; ++p)
            #pragma unroll
            for (int q = 0; q < 4; ++q)
                acc[p][q] = __builtin_amdgcn_mfma_f32_16x16x32_bf16(bh[q], ah[p], acc[p][q], 0, 0, 0);
        #pragma unroll
        for (int p = 0; p < 2; ++p)
            #pragma unroll
            for (int q = 0; q < 4; ++q)
                acc[p][q] = __builtin_amdgcn_mfma_f32_16x16x32_bf16(bl[q], ah[p], acc[p][q], 0, 0, 0);
        #pragma unroll
        for (int p = 0; p < 2; ++p)
            #pragma unroll
            for (int q = 0; q < 4; ++q)
                acc[p][q] = __builtin_amdgcn_mfma_f32_16x16x32_bf16(bh[q], al[p], acc[p][q], 0, 0, 0);
    }

    // ---- epilogue: D^T => lane holds row (i0+wr+p*16+fr), cols (wc+q*16+kg*4 .. +3)
    #pragma unroll
    for (int p = 0; p < 2; ++p) {
        int ri = wr + p * 16 + fr;
        float sa = sq[i0 + ri];
        float* rowp = out + (size_t)(i0 + ri) * N + j0;
        #pragma unroll
        for (int q = 0; q < 4; ++q) {
            int c = wc + q * 16 + kg * 4;
            float4 sb = *(const float4*)&sq[j0 + c];
            f32x4 a = acc[p][q];
            float4 r;
            r.x = __expf(-GAMMA * fmaxf(fmaf(-2.f, a[0], sa + sb.x), 0.f));
            r.y = __expf(-GAMMA * fmaxf(fmaf(-2.f, a[1], sa + sb.y), 0.f));
            r.z = __expf(-GAMMA * fmaxf(fmaf(-2.f, a[2], sa + sb.z), 0.f));
            r.w = __expf(-GAMMA * fmaxf(fmaf(-2.f, a[3], sa + sb.w), 0.f));
            *(float4*)(rowp + c) = r;
        }
    }
}

extern "C" void kernel_launch(void* const* d_in, const int* in_sizes, int n_in,
                              void* d_out, int out_size, void* d_ws, size_t ws_size,
                              hipStream_t stream) {
    (void)n_in; (void)ws_size; (void)out_size;
    const float* x = (const float*)d_in[0];
    float* out = (float*)d_out;
    const int K = 64;
    const int N = in_sizes[0] / K;   // 8192

    unsigned short* Xh = (unsigned short*)d_ws;              // N*64 bf16 = 1 MB
    unsigned short* Xl = Xh + (size_t)N * K;                 // 1 MB
    float* sq = (float*)(Xl + (size_t)N * K);                // 32 KB

    split_kernel<<<dim3(N * K / 4 / 256), dim3(256), 0, stream>>>(x, Xh, Xl, sq);
    rbf_mfma5<<<dim3(N / 128, N / 64), dim3(256), 0, stream>>>(Xh, Xl, sq, out, N);
}

// Round 11
// 67.675 us; speedup vs baseline: 1.5403x; 1.0575x over previous
//
#include <hip/hip_runtime.h>

// RBF Gram via bf16-split MFMA, two-phase:
//   P1: x (fp32 [N][64]) -> Xh,Xl (bf16, XOR-swizzled per 128-row chunk) + sq[N] in d_ws
//   P2: 128x128 tile per block, 512 threads (8 waves, each a 32x64 quadrant).
//       64 KB LDS -> 2 blocks/CU; VGPR<=128 (launch_bounds) -> 16 waves/CU.
//       dot = hh + hl + lh on matrix cores (lo*lo dropped; ~1e-13 abs err).
//       Swapped-operand MFMA (D^T) -> each lane owns 4 consecutive out cols -> dwordx4.
//       out = exp(-0.5*(sq_i+sq_j-2dot)).

#define GAMMA 0.5f

typedef __attribute__((ext_vector_type(8))) short short8;
typedef __attribute__((ext_vector_type(4))) float f32x4;

__device__ __forceinline__ unsigned short bf16_rne(float f) {
    unsigned u = __builtin_bit_cast(unsigned, f);
    u += 0x7fffu + ((u >> 16) & 1u);
    return (unsigned short)(u >> 16);
}

// ---------------- Phase 1: split + swizzle + norms ----------------
__global__ __launch_bounds__(256) void split_kernel(const float* __restrict__ x,
                                                    unsigned short* __restrict__ Xh,
                                                    unsigned short* __restrict__ Xl,
                                                    float* __restrict__ sq) {
    int tid = blockIdx.x * 256 + threadIdx.x;   // one float4 (4 elems of one row)
    int row = tid >> 4, c4 = tid & 15;
    float4 v = ((const float4*)x)[tid];
    float e[4] = {v.x, v.y, v.z, v.w};
    unsigned short h[4], l[4];
    float s = 0.f;
    #pragma unroll
    for (int i = 0; i < 4; ++i) {
        h[i] = bf16_rne(e[i]);
        float hf = __builtin_bit_cast(float, (unsigned)h[i] << 16);
        l[i] = bf16_rne(e[i] - hf);
        s = fmaf(e[i], e[i], s);
    }
    // byte offset within the 16KB 128-row chunk; XOR is row-local (bits 4..6 by row&7)
    int rr = row & 127;
    size_t base = (size_t)(row >> 7) * 16384;
    int b = (rr * 128 + c4 * 8) ^ ((rr & 7) << 4);
    uint2 hw = {(unsigned)h[0] | ((unsigned)h[1] << 16), (unsigned)h[2] | ((unsigned)h[3] << 16)};
    uint2 lw = {(unsigned)l[0] | ((unsigned)l[1] << 16), (unsigned)l[2] | ((unsigned)l[3] << 16)};
    *(uint2*)((char*)Xh + base + b) = hw;
    *(uint2*)((char*)Xl + base + b) = lw;
    s += __shfl_xor(s, 1); s += __shfl_xor(s, 2);
    s += __shfl_xor(s, 4); s += __shfl_xor(s, 8);
    if (c4 == 0) sq[row] = s;
}

// ---------------- Phase 2: 128x128 tile, 8 waves, MFMA + exp epilogue ----------------
__global__ __launch_bounds__(512, 4) void rbf_mfma6(const unsigned short* __restrict__ Xh,
                                                    const unsigned short* __restrict__ Xl,
                                                    const float* __restrict__ sq,
                                                    float* __restrict__ out, int N) {
    __shared__ unsigned short Ah[8192], Al[8192], Bh[8192], Bl[8192];  // 64 KB

    const int tid = threadIdx.x;
    const int i0 = blockIdx.y * 128, j0 = blockIdx.x * 128;
    const int w = tid >> 6, lane = tid & 63;
    const int fr = lane & 15, kg = lane >> 4;
    const int wr = (w >> 1) * 32, wc = (w & 1) * 64;   // wave sub-tile 32x64

    // ---- stage: linear 64KB copy (swizzle pre-baked in global layout) ----
    {
        const uint4* gha = (const uint4*)(Xh + (size_t)i0 * 64);
        const uint4* gla = (const uint4*)(Xl + (size_t)i0 * 64);
        const uint4* ghb = (const uint4*)(Xh + (size_t)j0 * 64);
        const uint4* glb = (const uint4*)(Xl + (size_t)j0 * 64);
        #pragma unroll
        for (int t = 0; t < 2; ++t) {
            ((uint4*)Ah)[t * 512 + tid] = gha[t * 512 + tid];
            ((uint4*)Al)[t * 512 + tid] = gla[t * 512 + tid];
            ((uint4*)Bh)[t * 512 + tid] = ghb[t * 512 + tid];
            ((uint4*)Bl)[t * 512 + tid] = glb[t * 512 + tid];
        }
    }
    __syncthreads();

    // ---- K-loop: 2 ksteps x 3 passes (hh, hl, lh), swapped operands -> D^T ----
    f32x4 acc[2][4];
    #pragma unroll
    for (int p = 0; p < 2; ++p)
        #pragma unroll
        for (int q = 0; q < 4; ++q) acc[p][q] = (f32x4)(0.f);

    #pragma unroll
    for (int ks = 0; ks < 2; ++ks) {
        const int kb = ks * 64 + kg * 16;   // byte offset of this lane's 16B k-slice
        short8 ah[2], al[2], bh[4], bl[4];
        #pragma unroll
        for (int p = 0; p < 2; ++p) {
            int R = wr + p * 16 + fr;
            int off = (R * 128 + kb) ^ ((R & 7) << 4);
            ah[p] = *(const short8*)((const char*)Ah + off);
            al[p] = *(const short8*)((const char*)Al + off);
        }
        #pragma unroll
        for (int q = 0; q < 4; ++q) {
            int R = wc + q * 16 + fr;
            int off = (R * 128 + kb) ^ ((R & 7) << 4);
            bh[q] = *(const short8*)((const char*)Bh + off);
            bl[q] = *(const short8*)((const char*)Bl + off);
        }
        #pragma unroll
        for (int p = 0; p < 2; ++p)
            #pragma unroll
            for (int q = 0; q < 4; ++q)
                acc[p][q] = __builtin_amdgcn_mfma_f32_16x16x32_bf16(bh[q], ah[p], acc[p][q], 0, 0, 0);
        #pragma unroll
        for (int p = 0; p < 2; ++p)
            #pragma unroll
            for (int q = 0; q < 4; ++q)
                acc[p][q] = __builtin_amdgcn_mfma_f32_16x16x32_bf16(bl[q], ah[p], acc[p][q], 0, 0, 0);
        #pragma unroll
        for (int p = 0; p < 2; ++p)
            #pragma unroll
            for (int q = 0; q < 4; ++q)
                acc[p][q] = __builtin_amdgcn_mfma_f32_16x16x32_bf16(bh[q], al[p], acc[p][q], 0, 0, 0);
    }

    // ---- epilogue: D^T => lane holds row (i0+wr+p*16+fr), cols (wc+q*16+kg*4 .. +3)
    #pragma unroll
    for (int p = 0; p < 2; ++p) {
        int ri = wr + p * 16 + fr;
        float sa = sq[i0 + ri];
        float* rowp = out + (size_t)(i0 + ri) * N + j0;
        #pragma unroll
        for (int q = 0; q < 4; ++q) {
            int c = wc + q * 16 + kg * 4;
            float4 sb = *(const float4*)&sq[j0 + c];
            f32x4 a = acc[p][q];
            float4 r;
            r.x = __expf(-GAMMA * fmaxf(fmaf(-2.f, a[0], sa + sb.x), 0.f));
            r.y = __expf(-GAMMA * fmaxf(fmaf(-2.f, a[1], sa + sb.y), 0.f));
            r.z = __expf(-GAMMA * fmaxf(fmaf(-2.f, a[2], sa + sb.z), 0.f));
            r.w = __expf(-GAMMA * fmaxf(fmaf(-2.f, a[3], sa + sb.w), 0.f));
            *(float4*)(rowp + c) = r;
        }
    }
}

extern "C" void kernel_launch(void* const* d_in, const int* in_sizes, int n_in,
                              void* d_out, int out_size, void* d_ws, size_t ws_size,
                              hipStream_t stream) {
    (void)n_in; (void)ws_size; (void)out_size;
    const float* x = (const float*)d_in[0];
    float* out = (float*)d_out;
    const int K = 64;
    const int N = in_sizes[0] / K;   // 8192

    unsigned short* Xh = (unsigned short*)d_ws;              // N*64 bf16 = 1 MB
    unsigned short* Xl = Xh + (size_t)N * K;                 // 1 MB
    float* sq = (float*)(Xl + (size_t)N * K);                // 32 KB

    split_kernel<<<dim3(N * K / 4 / 256), dim3(256), 0, stream>>>(x, Xh, Xl, sq);
    rbf_mfma6<<<dim3(N / 128, N / 128), dim3(512), 0, stream>>>(Xh, Xl, sq, out, N);
}

// Round 12
// 61.663 us; speedup vs baseline: 1.6905x; 1.0975x over previous
//
#include <hip/hip_runtime.h>

// RBF Gram via single-pass fp16 MFMA with quantization-cancelling norms:
//   P1: x (fp32 [N][64]) -> H (fp16, XOR-swizzled per 128-row chunk) AND
//       sq[i] = ||fp16(x_i)||^2 in fp32. Using the SAME quantized vectors for
//       norms and dots makes the kernel compute exactly ||h_i-h_j||^2 (fp16
//       products are exact in fp32 accum), so error vs ref scales like
//       sqrt(d2)*2^-8 -> ~2e-3 max where exp(-d2/2) is non-negligible.
//   P2: 128x128 tile, 4 waves (64x64 quadrants), 32 KB LDS -> 4 blocks/CU.
//       Swapped-operand MFMA (D^T) -> dwordx4 stores. out = exp(-0.5*d2).

#define GAMMA 0.5f

typedef __attribute__((ext_vector_type(8))) _Float16 half8;
typedef __attribute__((ext_vector_type(4))) float f32x4;

// ---------------- Phase 1: fp16 quantize + swizzle + quantized norms ----------------
__global__ __launch_bounds__(256) void quant_kernel(const float* __restrict__ x,
                                                    unsigned short* __restrict__ H,
                                                    float* __restrict__ sq) {
    int tid = blockIdx.x * 256 + threadIdx.x;   // one float4 (4 elems of one row)
    int row = tid >> 4, c4 = tid & 15;
    float4 v = ((const float4*)x)[tid];
    float e[4] = {v.x, v.y, v.z, v.w};
    unsigned short hb[4];
    float s = 0.f;
    #pragma unroll
    for (int i = 0; i < 4; ++i) {
        _Float16 h = (_Float16)e[i];            // RNE
        float hf = (float)h;
        s = fmaf(hf, hf, s);                    // norm of the QUANTIZED vector
        hb[i] = __builtin_bit_cast(unsigned short, h);
    }
    // byte offset within the 16KB 128-row chunk; XOR is row-local (bits 4..6 by row&7)
    int rr = row & 127;
    size_t base = (size_t)(row >> 7) * 16384;
    int b = (rr * 128 + c4 * 8) ^ ((rr & 7) << 4);
    uint2 hw = {(unsigned)hb[0] | ((unsigned)hb[1] << 16),
                (unsigned)hb[2] | ((unsigned)hb[3] << 16)};
    *(uint2*)((char*)H + base + b) = hw;
    s += __shfl_xor(s, 1); s += __shfl_xor(s, 2);
    s += __shfl_xor(s, 4); s += __shfl_xor(s, 8);
    if (c4 == 0) sq[row] = s;
}

// ---------------- Phase 2: 128x128 tile, single-pass fp16 MFMA + exp ----------------
__global__ __launch_bounds__(256, 4) void rbf_mfma7(const unsigned short* __restrict__ H,
                                                    const float* __restrict__ sq,
                                                    float* __restrict__ out, int N) {
    __shared__ unsigned short Ah[8192], Bh[8192];   // 16 KB + 16 KB = 32 KB

    const int tid = threadIdx.x;
    const int i0 = blockIdx.y * 128, j0 = blockIdx.x * 128;
    const int w = tid >> 6, lane = tid & 63;
    const int fr = lane & 15, kg = lane >> 4;
    const int wr = (w >> 1) * 64, wc = (w & 1) * 64;   // wave quadrant of 128x128

    // ---- stage: linear 32KB copy (swizzle pre-baked in global layout) ----
    {
        const uint4* ga = (const uint4*)(H + (size_t)i0 * 64);
        const uint4* gb = (const uint4*)(H + (size_t)j0 * 64);
        #pragma unroll
        for (int t = 0; t < 4; ++t) {
            ((uint4*)Ah)[t * 256 + tid] = ga[t * 256 + tid];
            ((uint4*)Bh)[t * 256 + tid] = gb[t * 256 + tid];
        }
    }
    __syncthreads();

    // ---- K-loop: 2 ksteps, single pass, swapped operands -> D^T ----
    f32x4 acc[4][4];
    #pragma unroll
    for (int p = 0; p < 4; ++p)
        #pragma unroll
        for (int q = 0; q < 4; ++q) acc[p][q] = (f32x4)(0.f);

    #pragma unroll
    for (int ks = 0; ks < 2; ++ks) {
        const int kb = ks * 64 + kg * 16;   // byte offset of this lane's 16B k-slice
        half8 ah[4], bh[4];
        #pragma unroll
        for (int p = 0; p < 4; ++p) {
            int R = wr + p * 16 + fr;
            int off = (R * 128 + kb) ^ ((R & 7) << 4);
            ah[p] = *(const half8*)((const char*)Ah + off);
        }
        #pragma unroll
        for (int q = 0; q < 4; ++q) {
            int R = wc + q * 16 + fr;
            int off = (R * 128 + kb) ^ ((R & 7) << 4);
            bh[q] = *(const half8*)((const char*)Bh + off);
        }
        #pragma unroll
        for (int p = 0; p < 4; ++p)
            #pragma unroll
            for (int q = 0; q < 4; ++q)
                acc[p][q] = __builtin_amdgcn_mfma_f32_16x16x32_f16(bh[q], ah[p], acc[p][q], 0, 0, 0);
    }

    // ---- epilogue: D^T => lane holds row (i0+wr+p*16+fr), cols (wc+q*16+kg*4 .. +3)
    #pragma unroll
    for (int p = 0; p < 4; ++p) {
        int ri = wr + p * 16 + fr;
        float sa = sq[i0 + ri];
        float* rowp = out + (size_t)(i0 + ri) * N + j0;
        #pragma unroll
        for (int q = 0; q < 4; ++q) {
            int c = wc + q * 16 + kg * 4;
            float4 sb = *(const float4*)&sq[j0 + c];
            f32x4 a = acc[p][q];
            float4 r;
            r.x = __expf(-GAMMA * fmaxf(fmaf(-2.f, a[0], sa + sb.x), 0.f));
            r.y = __expf(-GAMMA * fmaxf(fmaf(-2.f, a[1], sa + sb.y), 0.f));
            r.z = __expf(-GAMMA * fmaxf(fmaf(-2.f, a[2], sa + sb.z), 0.f));
            r.w = __expf(-GAMMA * fmaxf(fmaf(-2.f, a[3], sa + sb.w), 0.f));
            *(float4*)(rowp + c) = r;
        }
    }
}

extern "C" void kernel_launch(void* const* d_in, const int* in_sizes, int n_in,
                              void* d_out, int out_size, void* d_ws, size_t ws_size,
                              hipStream_t stream) {
    (void)n_in; (void)ws_size; (void)out_size;
    const float* x = (const float*)d_in[0];
    float* out = (float*)d_out;
    const int K = 64;
    const int N = in_sizes[0] / K;   // 8192

    unsigned short* H = (unsigned short*)d_ws;       // N*64 fp16 = 1 MB
    float* sq = (float*)(H + (size_t)N * K);         // 32 KB

    quant_kernel<<<dim3(N * K / 4 / 256), dim3(256), 0, stream>>>(x, H, sq);
    rbf_mfma7<<<dim3(N / 128, N / 128), dim3(256), 0, stream>>>(H, sq, out, N);
}